// Round 9
// baseline (237.073 us; speedup 1.0000x reference)
//
#include <hip/hip_runtime.h>
#include <cstdint>
#include <cstddef>

typedef __bf16 bf16;
typedef __bf16 bf16x8 __attribute__((ext_vector_type(8)));
typedef __bf16 bf16x4v __attribute__((ext_vector_type(4)));
typedef float  f32x4  __attribute__((ext_vector_type(4)));

#define MFMA(a, b, c) __builtin_amdgcn_mfma_f32_16x16x32_bf16((a), (b), (c), 0, 0, 0)

typedef __attribute__((address_space(3))) unsigned int  lds_u32;
typedef __attribute__((address_space(1))) unsigned int glob_u32;

// B=4, N=1024, DIM=768, HEADS=12, DIM_HEAD=64, INNER=768
// c2 = 0.5/sqrt(768)*log2(e) is folded into qcat by k_gemm12's epilogue.

// ---------------------------------------------------------------------------
// Merged prep: blocks [0,6144) = fp32->bf16 convert of x|pos;
// blocks [6144,9600) = transposing convert of the 3 weights.
// ---------------------------------------------------------------------------
__global__ void k_prep(const float* __restrict__ x, const float* __restrict__ pos,
                       const float* __restrict__ w_qkv, const float* __restrict__ w_qk_pos,
                       const float* __restrict__ w_out,
                       bf16* __restrict__ xb, bf16* __restrict__ posb,
                       bf16* __restrict__ wqkvT, bf16* __restrict__ wqkposT,
                       bf16* __restrict__ woutT) {
    __shared__ float t[32][33];
    const int blk = blockIdx.x;
    if (blk < 6144) {
        int i = blk * 256 + threadIdx.x;
        const float* in = x; bf16* out = xb;
        if (i >= 786432) { i -= 786432; in = pos; out = posb; }
        float4 v = reinterpret_cast<const float4*>(in)[i];
        bf16x4v o; o[0] = (bf16)v.x; o[1] = (bf16)v.y; o[2] = (bf16)v.z; o[3] = (bf16)v.w;
        reinterpret_cast<bf16x4v*>(out)[i] = o;
        return;
    }
    int bx = (blk - 6144) % 144, ky = (blk - 6144) / 144;
    const float* in; bf16* out; int N;
    if (bx < 72)       { in = w_qkv;    out = wqkvT;   N = 2304; }
    else if (bx < 120) { in = w_qk_pos; out = wqkposT; N = 1536; bx -= 72; }
    else               { in = w_out;    out = woutT;   N = 768;  bx -= 120; }
    const int n0 = bx * 32, k0 = ky * 32;
    const int tx = threadIdx.x & 31, ty = threadIdx.x >> 5;
#pragma unroll
    for (int r = 0; r < 32; r += 8)
        t[ty + r][tx] = in[(size_t)(k0 + ty + r) * N + n0 + tx];
    __syncthreads();
#pragma unroll
    for (int r = 0; r < 32; r += 8)
        out[(size_t)(n0 + ty + r) * 768 + k0 + tx] = (bf16)t[tx][ty + r];
}

// ---------------------------------------------------------------------------
// Merged GEMM for qkv (mode 0) and qk_pos (mode 1). 128x128 tile, both
// operands glds double-buffered into XOR-swizzled LDS (proven structure).
// XCD-aware 1D grid 960. qcat pre-scaled by c2.
// R6: reverted to the exact R0 body (best measured: 43.2 us, FETCH 21.7 MB).
// Five structural variants (launch_bounds 4, 3-buf counted vmcnt, BK=64,
// 256^2 tile) all landed 43-47 us: time = staged_bytes/(residency x ~7B/cyc),
// and no variant moved both factors favorably. Stop iterating here.
// ---------------------------------------------------------------------------
__launch_bounds__(256, 3)
__global__ void k_gemm12(const bf16* __restrict__ xb, const bf16* __restrict__ posb,
                         const bf16* __restrict__ wqkvT, const bf16* __restrict__ wqkposT,
                         bf16* __restrict__ qcat, bf16* __restrict__ kcat,
                         bf16* __restrict__ vT) {
    __shared__ bf16 lA[2][128][32];
    __shared__ bf16 lB[2][128][32];

    const int tid  = threadIdx.x;
    const int lane = tid & 63, wave = tid >> 6;
    const int quad = lane >> 4, col = lane & 15;
    const int sw2  = (col >> 1) & 3;
    const int wm = (wave >> 1) * 64, wn = (wave & 1) * 64;

    const int fid = blockIdx.x;
    const int xcd = fid & 7, s = fid >> 3;
    const int sx = s % 15, sy = s / 15;
    int bx = (xcd & 1) * 15 + sx;
    const int by = (xcd >> 1) * 8 + sy;

    int mode, nBase;
    const bf16 *A, *BT;
    if (bx < 18) { mode = 0; A = xb;   BT = wqkvT;   nBase = bx * 128; }
    else         { mode = 1; A = posb; BT = wqkposT; nBase = (bx - 18) * 128; }
    const int mBase = by * 128;

    const bf16* Ap = A  + (size_t)mBase * 768;
    const bf16* Bp = BT + (size_t)nBase * 768;

#define STAGE12(buf, k0)                                                        \
    _Pragma("unroll")                                                           \
    for (int j = 0; j < 2; ++j) {                                               \
        int idx = (wave * 2 + j) * 64 + lane;                                   \
        int row = idx >> 2, c = (idx & 3) ^ ((row >> 1) & 3);                   \
        __builtin_amdgcn_global_load_lds(                                       \
            (const glob_u32*)(Ap + (size_t)row * 768 + (k0) + c * 8),           \
            (lds_u32*)((char*)&lA[buf][0][0] + (wave * 2 + j) * 1024), 16, 0, 0);\
        __builtin_amdgcn_global_load_lds(                                       \
            (const glob_u32*)(Bp + (size_t)row * 768 + (k0) + c * 8),           \
            (lds_u32*)((char*)&lB[buf][0][0] + (wave * 2 + j) * 1024), 16, 0, 0);\
    }

    f32x4 acc[4][4];
#pragma unroll
    for (int mi = 0; mi < 4; ++mi)
#pragma unroll
        for (int ni = 0; ni < 4; ++ni) acc[mi][ni] = f32x4{0.f, 0.f, 0.f, 0.f};

    STAGE12(0, 0)
    for (int it = 0; it < 24; ++it) {
        const int cur = it & 1, nxt = cur ^ 1;
        __syncthreads();
        if (it < 23) STAGE12(nxt, (it + 1) * 32)

        bf16x8 af[4], bfg[4];
#pragma unroll
        for (int mi = 0; mi < 4; ++mi)
            af[mi]  = *(const bf16x8*)&lA[cur][wm + mi * 16 + col][(quad ^ sw2) * 8];
#pragma unroll
        for (int ni = 0; ni < 4; ++ni)
            bfg[ni] = *(const bf16x8*)&lB[cur][wn + ni * 16 + col][(quad ^ sw2) * 8];
#pragma unroll
        for (int mi = 0; mi < 4; ++mi)
#pragma unroll
            for (int ni = 0; ni < 4; ++ni)
                acc[mi][ni] = MFMA(af[mi], bfg[ni], acc[mi][ni]);
    }
#undef STAGE12

    const float c2s = 0.018042195912f * 1.44269504089f;
    const int bb = mBase >> 10;
    const int sr0 = (mBase & 1023) + wm + quad * 4;
#pragma unroll
    for (int ni = 0; ni < 4; ++ni) {
        const int nb = nBase + wn + ni * 16;
        const int which = (mode == 0) ? (nb >= 1536 ? 2 : (nb >= 768 ? 1 : 0))
                                      : (nb >= 768 ? 1 : 0);
        const int rem = nb - which * 768;
        const int hh = rem >> 6, dd0 = rem & 63;
        const size_t hb = (size_t)(bb * 12 + hh);
        if (mode == 0 && which == 2) {
            bf16* dstv = vT + (hb * 64 + dd0 + col) * 1024 + sr0;
#pragma unroll
            for (int mi = 0; mi < 4; ++mi) {
                bf16x4v pk;
#pragma unroll
                for (int r = 0; r < 4; ++r) pk[r] = (bf16)acc[mi][ni][r];
                *(bf16x4v*)(dstv + mi * 16) = pk;
            }
        } else {
            const float scl = (which == 0) ? c2s : 1.0f;
            bf16* dstq = (which == 0 ? qcat : kcat)
                       + (hb * 1024 + sr0) * 128 + (mode == 1 ? 64 : 0) + dd0 + col;
#pragma unroll
            for (int mi = 0; mi < 4; ++mi)
#pragma unroll
                for (int r = 0; r < 4; ++r)
                    dstq[(size_t)(mi * 16 + r) * 128] = (bf16)(acc[mi][ni][r] * scl);
        }
    }
}

// ---------------------------------------------------------------------------
// Flash attention v6: V LDS-staging REMOVED (guide m169: at S=1024 the V-unit
// is 128 KB and L2-resident, shared by 16 q-blocks -- staging it through
// LDS was pure per-iter overhead: 2 global b128 + vmcnt wait + 4 ds_write
// + lgkm on the critical path). PV now reads V fragments directly from
// global: the old sigma-permuted lV b128 at [d][c*32+quad*8+j] equals two
// global b64 at Vb[d*1024 + kv0 + c*32 + quad*4] and +16
// (kv = c*32 + (j>=4)*16 + quad*4 + (j&3); same mapping, re-derived).
// K staging via glds unchanged. LDS 50.6 -> 32 KB. Grid 768 XCD-pinned.
// ---------------------------------------------------------------------------
__launch_bounds__(256, 3)
__global__ void k_attn(const bf16* __restrict__ qcat, const bf16* __restrict__ kcat,
                       const bf16* __restrict__ vT, bf16* __restrict__ attn_out) {
    __shared__ bf16 lK[2][64][128];   // 32 KB, XOR-swizzled chunks (glds)

    const int tid  = threadIdx.x;
    const int lane = tid & 63, wave = tid >> 6;
    const int quad = lane >> 4, col = lane & 15;
    const int sw   = col & 7;

    const int fid = blockIdx.x;
    const int xcd = fid & 7, s = fid >> 3;
    const int qt = s & 15;
    const int unit = (s >> 4) * 8 + xcd;
    const int b = unit / 12, h = unit % 12;

    const bf16* Qb = qcat + (size_t)unit * 1024 * 128;
    const bf16* Kb = kcat + (size_t)unit * 1024 * 128;
    const bf16* Vb = vT   + (size_t)unit * 64 * 1024;

    const int kidx = wave * 256 + lane;

#define STAGE_K(buf, kv0)                                                      \
    _Pragma("unroll")                                                          \
    for (int j = 0; j < 4; ++j) {                                              \
        int idx = kidx + j * 64;                                               \
        int row = idx >> 4, c = idx & 15, csrc = c ^ (row & 7);                \
        __builtin_amdgcn_global_load_lds(                                      \
            (const glob_u32*)(Kb + (size_t)((kv0) + row) * 128 + csrc * 8),    \
            (lds_u32*)(&lK[buf][0][0] + (wave * 4 + j) * 512), 16, 0, 0);      \
    }

    // Q B-fragments for this wave's 16 q-rows (n=col, k=f*32+quad*8+j)
    bf16x8 qb[4];
    {
        const bf16* qrow = Qb + (size_t)(qt * 64 + wave * 16 + col) * 128;
#pragma unroll
        for (int f = 0; f < 4; ++f) qb[f] = *(const bf16x8*)(qrow + f * 32 + quad * 8);
    }

    // Per-lane V row base: PV A-fragment m-index = d = vt*16 + col.
    const bf16* Vrow0 = Vb + (size_t)col * 1024 + quad * 4;

    f32x4 o[4];
#pragma unroll
    for (int vt = 0; vt < 4; ++vt) o[vt] = f32x4{0.f, 0.f, 0.f, 0.f};
    float lsum = 0.f;

    STAGE_K(0, 0)

    for (int it = 0; it < 16; ++it) {
        const int cur = it & 1, nxt = cur ^ 1;
        __syncthreads();
        if (it < 15) STAGE_K(nxt, (it + 1) * 64)

        // S^T = K * Q^T : A-frag = K rows (m = kv_local = t*16+col)
        f32x4 st[4];
#pragma unroll
        for (int t = 0; t < 4; ++t) st[t] = f32x4{0.f, 0.f, 0.f, 0.f};
#pragma unroll
        for (int t = 0; t < 4; ++t)
#pragma unroll
            for (int f = 0; f < 4; ++f) {
                bf16x8 kf = *(const bf16x8*)&lK[cur][t * 16 + col][((f * 4 + quad) ^ sw) * 8];
                st[t] = MFMA(kf, qb[f], st[t]);
            }

        // p = exp2(s); pack into PV B-fragments (kv-interleave by register naming)
        bf16x8 pbf[2];
#pragma unroll
        for (int c = 0; c < 2; ++c) {
#pragma unroll
            for (int r = 0; r < 4; ++r) {
                float p0 = exp2f(st[2 * c][r]);
                float p1 = exp2f(st[2 * c + 1][r]);
                lsum += p0 + p1;
                pbf[c][r]     = (bf16)p0;
                pbf[c][4 + r] = (bf16)p1;
            }
        }

        // O^T += V^T * P^T ; V fragment = two b64 direct from global (L2-hot)
        const int kv0 = it * 64;
#pragma unroll
        for (int c = 0; c < 2; ++c)
#pragma unroll
            for (int vt = 0; vt < 4; ++vt) {
                const bf16* vp = Vrow0 + (size_t)vt * 16 * 1024 + kv0 + c * 32;
                bf16x4v lo = *(const bf16x4v*)(vp);
                bf16x4v hi = *(const bf16x4v*)(vp + 16);
                bf16x8 vf;
#pragma unroll
                for (int r = 0; r < 4; ++r) { vf[r] = lo[r]; vf[4 + r] = hi[r]; }
                o[vt] = MFMA(vf, pbf[c], o[vt]);
            }
    }

    float l = lsum;
    l += __shfl_xor(l, 16, 64);
    l += __shfl_xor(l, 32, 64);
    const float inv = 1.f / l;

    const int qrow = qt * 64 + wave * 16 + col;
    bf16* dst = attn_out + ((size_t)b * 1024 + qrow) * 768 + h * 64;
#pragma unroll
    for (int vt = 0; vt < 4; ++vt) {
        bf16x4v pk;
#pragma unroll
        for (int r = 0; r < 4; ++r) pk[r] = (bf16)(o[vt][r] * inv);
        *(bf16x4v*)(dst + vt * 16 + quad * 4) = pk;
    }
#undef STAGE_K
}

// ---------------------------------------------------------------------------
// Out projection: out[4096][768] = aout @ woutT^T + bias (fp32 out)
// 64m x 64n tiles -> 1D grid 768 (3 blocks/CU vs 1.5 at 128x64), glds
// double-buffered, XCD-aware (each XCD owns 12bx x 8by).
// ---------------------------------------------------------------------------
__launch_bounds__(256, 3)
__global__ void k_gemm_out(const bf16* __restrict__ aout, const bf16* __restrict__ woutT,
                           const float* __restrict__ bias, float* __restrict__ out) {
    __shared__ bf16 lA[2][64][32];
    __shared__ bf16 lB[2][64][32];

    const int tid  = threadIdx.x;
    const int lane = tid & 63, wave = tid >> 6;
    const int quad = lane >> 4, col = lane & 15;
    const int sw2  = (col >> 1) & 3;
    const int wm = (wave >> 1) * 32, wn = (wave & 1) * 32;

    const int fid = blockIdx.x;
    const int xcd = fid & 7, s = fid >> 3;     // s in [0,96)
    const int bx = s % 12;                     // [0,12)
    const int by = xcd * 8 + s / 12;           // [0,64)

    const int mBase = by * 64, nBase = bx * 64;

    const bf16* Ap = aout  + (size_t)mBase * 768;
    const bf16* Bp = woutT + (size_t)nBase * 768;

#define STAGE_O(buf, k0)                                                        \
    {                                                                           \
        int idx = wave * 64 + lane;                                             \
        int row = idx >> 2, c = (idx & 3) ^ ((row >> 1) & 3);                   \
        __builtin_amdgcn_global_load_lds(                                       \
            (const glob_u32*)(Ap + (size_t)row * 768 + (k0) + c * 8),           \
            (lds_u32*)((char*)&lA[buf][0][0] + wave * 1024), 16, 0, 0);         \
        __builtin_amdgcn_global_load_lds(                                       \
            (const glob_u32*)(Bp + (size_t)row * 768 + (k0) + c * 8),           \
            (lds_u32*)((char*)&lB[buf][0][0] + wave * 1024), 16, 0, 0);         \
    }

    f32x4 acc[2][2];
#pragma unroll
    for (int mi = 0; mi < 2; ++mi)
#pragma unroll
        for (int ni = 0; ni < 2; ++ni) acc[mi][ni] = f32x4{0.f, 0.f, 0.f, 0.f};

    STAGE_O(0, 0)
    for (int it = 0; it < 24; ++it) {
        const int cur = it & 1, nxt = cur ^ 1;
        __syncthreads();
        if (it < 23) STAGE_O(nxt, (it + 1) * 32)

        bf16x8 af[2], bfg[2];
#pragma unroll
        for (int mi = 0; mi < 2; ++mi)
            af[mi]  = *(const bf16x8*)&lA[cur][wm + mi * 16 + col][(quad ^ sw2) * 8];
#pragma unroll
        for (int ni = 0; ni < 2; ++ni)
            bfg[ni] = *(const bf16x8*)&lB[cur][wn + ni * 16 + col][(quad ^ sw2) * 8];
#pragma unroll
        for (int mi = 0; mi < 2; ++mi)
#pragma unroll
            for (int ni = 0; ni < 2; ++ni)
                acc[mi][ni] = MFMA(af[mi], bfg[ni], acc[mi][ni]);
    }
#undef STAGE_O

#pragma unroll
    for (int mi = 0; mi < 2; ++mi)
#pragma unroll
        for (int ni = 0; ni < 2; ++ni)
#pragma unroll
            for (int r = 0; r < 4; ++r) {
                int m = mBase + wm + mi * 16 + quad * 4 + r;
                int n = nBase + wn + ni * 16 + col;
                out[(size_t)m * 768 + n] = acc[mi][ni][r] + bias[n];
            }
}

// ---------------------------------------------------------------------------
// Workspace layout (bytes): total 57409536 B
// ---------------------------------------------------------------------------
extern "C" void kernel_launch(void* const* d_in, const int* in_sizes, int n_in,
                              void* d_out, int out_size, void* d_ws, size_t ws_size,
                              hipStream_t stream) {
    const float* x        = (const float*)d_in[0];
    const float* pos      = (const float*)d_in[1];
    const float* w_qkv    = (const float*)d_in[2];
    const float* w_qk_pos = (const float*)d_in[3];
    const float* w_out    = (const float*)d_in[4];
    const float* b_out    = (const float*)d_in[5];
    float* out = (float*)d_out;

    char* ws = (char*)d_ws;
    bf16* xb      = (bf16*)(ws);
    bf16* posb    = (bf16*)(ws + 6291456);
    bf16* wqkvT   = (bf16*)(ws + 12582912);
    bf16* wqkposT = (bf16*)(ws + 16121856);
    bf16* woutT   = (bf16*)(ws + 18481152);
    bf16* qcat    = (bf16*)(ws + 19660800);
    bf16* kcat    = (bf16*)(ws + 32243712);
    bf16* vT      = (bf16*)(ws + 44826624);
    bf16* aout    = (bf16*)(ws + 51118080);

    k_prep<<<9600, 256, 0, stream>>>(x, pos, w_qkv, w_qk_pos, w_out,
                                     xb, posb, wqkvT, wqkposT, woutT);
    k_gemm12<<<960, 256, 0, stream>>>(xb, posb, wqkvT, wqkposT, qcat, kcat, vT);
    k_attn<<<768, 256, 0, stream>>>(qcat, kcat, vT, aout);
    k_gemm_out<<<768, 256, 0, stream>>>(aout, woutT, b_out, out);
}

// Round 10
// 175.948 us; speedup vs baseline: 1.3474x; 1.3474x over previous
//
#include <hip/hip_runtime.h>
#include <cstdint>
#include <cstddef>

typedef __bf16 bf16;
typedef __bf16 bf16x8 __attribute__((ext_vector_type(8)));
typedef __bf16 bf16x4v __attribute__((ext_vector_type(4)));
typedef float  f32x4  __attribute__((ext_vector_type(4)));

#define MFMA(a, b, c) __builtin_amdgcn_mfma_f32_16x16x32_bf16((a), (b), (c), 0, 0, 0)

typedef __attribute__((address_space(3))) unsigned int  lds_u32;
typedef __attribute__((address_space(1))) unsigned int glob_u32;

// B=4, N=1024, DIM=768, HEADS=12, DIM_HEAD=64, INNER=768
// c2 = 0.5/sqrt(768)*log2(e) is folded into qcat by k_gemm12's epilogue.

// ---------------------------------------------------------------------------
// Merged prep: blocks [0,6144) = fp32->bf16 convert of x|pos;
// blocks [6144,9600) = transposing convert of the 3 weights.
// ---------------------------------------------------------------------------
__global__ void k_prep(const float* __restrict__ x, const float* __restrict__ pos,
                       const float* __restrict__ w_qkv, const float* __restrict__ w_qk_pos,
                       const float* __restrict__ w_out,
                       bf16* __restrict__ xb, bf16* __restrict__ posb,
                       bf16* __restrict__ wqkvT, bf16* __restrict__ wqkposT,
                       bf16* __restrict__ woutT) {
    __shared__ float t[32][33];
    const int blk = blockIdx.x;
    if (blk < 6144) {
        int i = blk * 256 + threadIdx.x;
        const float* in = x; bf16* out = xb;
        if (i >= 786432) { i -= 786432; in = pos; out = posb; }
        float4 v = reinterpret_cast<const float4*>(in)[i];
        bf16x4v o; o[0] = (bf16)v.x; o[1] = (bf16)v.y; o[2] = (bf16)v.z; o[3] = (bf16)v.w;
        reinterpret_cast<bf16x4v*>(out)[i] = o;
        return;
    }
    int bx = (blk - 6144) % 144, ky = (blk - 6144) / 144;
    const float* in; bf16* out; int N;
    if (bx < 72)       { in = w_qkv;    out = wqkvT;   N = 2304; }
    else if (bx < 120) { in = w_qk_pos; out = wqkposT; N = 1536; bx -= 72; }
    else               { in = w_out;    out = woutT;   N = 768;  bx -= 120; }
    const int n0 = bx * 32, k0 = ky * 32;
    const int tx = threadIdx.x & 31, ty = threadIdx.x >> 5;
#pragma unroll
    for (int r = 0; r < 32; r += 8)
        t[ty + r][tx] = in[(size_t)(k0 + ty + r) * N + n0 + tx];
    __syncthreads();
#pragma unroll
    for (int r = 0; r < 32; r += 8)
        out[(size_t)(n0 + ty + r) * 768 + k0 + tx] = (bf16)t[tx][ty + r];
}

// ---------------------------------------------------------------------------
// Merged GEMM for qkv (mode 0) and qk_pos (mode 1). 128x128 tile, both
// operands glds double-buffered into XOR-swizzled LDS (proven structure).
// XCD-aware 1D grid 960. qcat pre-scaled by c2.
// R6/R9: exact R0 body (best measured: 43.2 us, FETCH 21.7 MB). Five
// structural variants (launch_bounds 4, 3-buf counted vmcnt, BK=64, 256^2)
// all landed 43-47 us: time = staged_bytes/(residency x ~7B/cyc); no
// variant moved both factors favorably. Locked.
// ---------------------------------------------------------------------------
__launch_bounds__(256, 3)
__global__ void k_gemm12(const bf16* __restrict__ xb, const bf16* __restrict__ posb,
                         const bf16* __restrict__ wqkvT, const bf16* __restrict__ wqkposT,
                         bf16* __restrict__ qcat, bf16* __restrict__ kcat,
                         bf16* __restrict__ vT) {
    __shared__ bf16 lA[2][128][32];
    __shared__ bf16 lB[2][128][32];

    const int tid  = threadIdx.x;
    const int lane = tid & 63, wave = tid >> 6;
    const int quad = lane >> 4, col = lane & 15;
    const int sw2  = (col >> 1) & 3;
    const int wm = (wave >> 1) * 64, wn = (wave & 1) * 64;

    const int fid = blockIdx.x;
    const int xcd = fid & 7, s = fid >> 3;
    const int sx = s % 15, sy = s / 15;
    int bx = (xcd & 1) * 15 + sx;
    const int by = (xcd >> 1) * 8 + sy;

    int mode, nBase;
    const bf16 *A, *BT;
    if (bx < 18) { mode = 0; A = xb;   BT = wqkvT;   nBase = bx * 128; }
    else         { mode = 1; A = posb; BT = wqkposT; nBase = (bx - 18) * 128; }
    const int mBase = by * 128;

    const bf16* Ap = A  + (size_t)mBase * 768;
    const bf16* Bp = BT + (size_t)nBase * 768;

#define STAGE12(buf, k0)                                                        \
    _Pragma("unroll")                                                           \
    for (int j = 0; j < 2; ++j) {                                               \
        int idx = (wave * 2 + j) * 64 + lane;                                   \
        int row = idx >> 2, c = (idx & 3) ^ ((row >> 1) & 3);                   \
        __builtin_amdgcn_global_load_lds(                                       \
            (const glob_u32*)(Ap + (size_t)row * 768 + (k0) + c * 8),           \
            (lds_u32*)((char*)&lA[buf][0][0] + (wave * 2 + j) * 1024), 16, 0, 0);\
        __builtin_amdgcn_global_load_lds(                                       \
            (const glob_u32*)(Bp + (size_t)row * 768 + (k0) + c * 8),           \
            (lds_u32*)((char*)&lB[buf][0][0] + (wave * 2 + j) * 1024), 16, 0, 0);\
    }

    f32x4 acc[4][4];
#pragma unroll
    for (int mi = 0; mi < 4; ++mi)
#pragma unroll
        for (int ni = 0; ni < 4; ++ni) acc[mi][ni] = f32x4{0.f, 0.f, 0.f, 0.f};

    STAGE12(0, 0)
    for (int it = 0; it < 24; ++it) {
        const int cur = it & 1, nxt = cur ^ 1;
        __syncthreads();
        if (it < 23) STAGE12(nxt, (it + 1) * 32)

        bf16x8 af[4], bfg[4];
#pragma unroll
        for (int mi = 0; mi < 4; ++mi)
            af[mi]  = *(const bf16x8*)&lA[cur][wm + mi * 16 + col][(quad ^ sw2) * 8];
#pragma unroll
        for (int ni = 0; ni < 4; ++ni)
            bfg[ni] = *(const bf16x8*)&lB[cur][wn + ni * 16 + col][(quad ^ sw2) * 8];
#pragma unroll
        for (int mi = 0; mi < 4; ++mi)
#pragma unroll
            for (int ni = 0; ni < 4; ++ni)
                acc[mi][ni] = MFMA(af[mi], bfg[ni], acc[mi][ni]);
    }
#undef STAGE12

    const float c2s = 0.018042195912f * 1.44269504089f;
    const int bb = mBase >> 10;
    const int sr0 = (mBase & 1023) + wm + quad * 4;
#pragma unroll
    for (int ni = 0; ni < 4; ++ni) {
        const int nb = nBase + wn + ni * 16;
        const int which = (mode == 0) ? (nb >= 1536 ? 2 : (nb >= 768 ? 1 : 0))
                                      : (nb >= 768 ? 1 : 0);
        const int rem = nb - which * 768;
        const int hh = rem >> 6, dd0 = rem & 63;
        const size_t hb = (size_t)(bb * 12 + hh);
        if (mode == 0 && which == 2) {
            bf16* dstv = vT + (hb * 64 + dd0 + col) * 1024 + sr0;
#pragma unroll
            for (int mi = 0; mi < 4; ++mi) {
                bf16x4v pk;
#pragma unroll
                for (int r = 0; r < 4; ++r) pk[r] = (bf16)acc[mi][ni][r];
                *(bf16x4v*)(dstv + mi * 16) = pk;
            }
        } else {
            const float scl = (which == 0) ? c2s : 1.0f;
            bf16* dstq = (which == 0 ? qcat : kcat)
                       + (hb * 1024 + sr0) * 128 + (mode == 1 ? 64 : 0) + dd0 + col;
#pragma unroll
            for (int mi = 0; mi < 4; ++mi)
#pragma unroll
                for (int r = 0; r < 4; ++r)
                    dstq[(size_t)(mi * 16 + r) * 128] = (bf16)(acc[mi][ni][r] * scl);
        }
    }
}

// ---------------------------------------------------------------------------
// Flash attention v5 (REVERTED from v6): register-resident P + conflict-free
// V via PADDED [64][72] sigma-permuted LDS tile. R9 post-mortem: v6's
// "direct-from-global V" was address-divergent (lane stride 2KB -> each b64
// load touches 64 cache lines; TA serializes) -> attn 36 -> 99 us. The LDS
// sigma-permutation exists precisely to make the staging loads coalesced.
// R9 addition: T5 s_setprio(1/0) around both MFMA clusters — guide m191:
// +4-7% on attn when co-resident blocks are phase-diverse (3 independent
// blocks/CU here); null only for lockstep GEMM (m190), so NOT applied there.
// K staging via glds. LDS 50.6 KB -> 3 blocks/CU. Grid 768 XCD-pinned.
// ---------------------------------------------------------------------------
__launch_bounds__(256, 3)
__global__ void k_attn(const bf16* __restrict__ qcat, const bf16* __restrict__ kcat,
                       const bf16* __restrict__ vT, bf16* __restrict__ attn_out) {
    __shared__ bf16 lK[2][64][128];   // 32 KB, XOR-swizzled chunks (glds)
    __shared__ bf16 lV[2][64][72];    // 18.4 KB, padded + sigma-permuted

    const int tid  = threadIdx.x;
    const int lane = tid & 63, wave = tid >> 6;
    const int quad = lane >> 4, col = lane & 15;
    const int sw   = col & 7;

    const int fid = blockIdx.x;
    const int xcd = fid & 7, s = fid >> 3;
    const int qt = s & 15;
    const int unit = (s >> 4) * 8 + xcd;
    const int b = unit / 12, h = unit % 12;

    const bf16* Qb = qcat + (size_t)unit * 1024 * 128;
    const bf16* Kb = kcat + (size_t)unit * 1024 * 128;
    const bf16* Vb = vT   + (size_t)unit * 64 * 1024;

    const int kidx = wave * 256 + lane;

#define STAGE_K(buf, kv0)                                                      \
    _Pragma("unroll")                                                          \
    for (int j = 0; j < 4; ++j) {                                              \
        int idx = kidx + j * 64;                                               \
        int row = idx >> 4, c = idx & 15, csrc = c ^ (row & 7);                \
        __builtin_amdgcn_global_load_lds(                                      \
            (const glob_u32*)(Kb + (size_t)((kv0) + row) * 128 + csrc * 8),    \
            (lds_u32*)(&lK[buf][0][0] + (wave * 4 + j) * 512), 16, 0, 0);      \
    }

    // V staging coords: cid = wave*128 + j*64 + lane, j in {0,1}
    //   source: Vb[vd][kv0 + sck*8 .. +7]   (b128)
    //   dest:   lV[buf][vd][kva], lV[buf][vd][kva+8]  (2x b64)
    int vdj[2], vsk[2], vka[2];
#pragma unroll
    for (int j = 0; j < 2; ++j) {
        int cid = wave * 128 + j * 64 + lane;
        vdj[j] = cid >> 3;
        int sck = cid & 7;
        vsk[j] = sck * 8;
        vka[j] = (sck >> 2) * 32 + (sck & 1) * 16 + ((sck >> 1) & 1) * 4;
    }

#define LOAD_V(kv0)                                                            \
    _Pragma("unroll")                                                          \
    for (int j = 0; j < 2; ++j)                                                \
        vreg[j] = *(const uint4*)(Vb + (size_t)vdj[j] * 1024 + (kv0) + vsk[j]);
#define WRITE_V(buf)                                                           \
    _Pragma("unroll")                                                          \
    for (int j = 0; j < 2; ++j) {                                               \
        *(uint2*)&lV[buf][vdj[j]][vka[j]]     = make_uint2(vreg[j].x, vreg[j].y);\
        *(uint2*)&lV[buf][vdj[j]][vka[j] + 8] = make_uint2(vreg[j].z, vreg[j].w);\
    }

    // Q B-fragments for this wave's 16 q-rows (n=col, k=f*32+quad*8+j)
    bf16x8 qb[4];
    {
        const bf16* qrow = Qb + (size_t)(qt * 64 + wave * 16 + col) * 128;
#pragma unroll
        for (int f = 0; f < 4; ++f) qb[f] = *(const bf16x8*)(qrow + f * 32 + quad * 8);
    }

    f32x4 o[4];
#pragma unroll
    for (int vt = 0; vt < 4; ++vt) o[vt] = f32x4{0.f, 0.f, 0.f, 0.f};
    float lsum = 0.f;

    uint4 vreg[2];
    STAGE_K(0, 0)
    LOAD_V(0)
    WRITE_V(0)

    for (int it = 0; it < 16; ++it) {
        const int cur = it & 1, nxt = cur ^ 1;
        __syncthreads();
        if (it < 15) {
            const int kv1 = (it + 1) * 64;
            STAGE_K(nxt, kv1)
            LOAD_V(kv1)
        }

        // S^T = K * Q^T : A-frag = K rows (m = kv_local = t*16+col)
        f32x4 st[4];
#pragma unroll
        for (int t = 0; t < 4; ++t) st[t] = f32x4{0.f, 0.f, 0.f, 0.f};
        __builtin_amdgcn_s_setprio(1);
#pragma unroll
        for (int t = 0; t < 4; ++t)
#pragma unroll
            for (int f = 0; f < 4; ++f) {
                bf16x8 kf = *(const bf16x8*)&lK[cur][t * 16 + col][((f * 4 + quad) ^ sw) * 8];
                st[t] = MFMA(kf, qb[f], st[t]);
            }
        __builtin_amdgcn_s_setprio(0);

        // p = exp2(s); pack into PV B-fragments (kv-interleave by register naming)
        bf16x8 pbf[2];
#pragma unroll
        for (int c = 0; c < 2; ++c) {
#pragma unroll
            for (int r = 0; r < 4; ++r) {
                float p0 = exp2f(st[2 * c][r]);
                float p1 = exp2f(st[2 * c + 1][r]);
                lsum += p0 + p1;
                pbf[c][r]     = (bf16)p0;
                pbf[c][4 + r] = (bf16)p1;
            }
        }

        // O^T += V^T * P^T ; V fragment = ONE b128 from sigma-permuted tile
        __builtin_amdgcn_s_setprio(1);
#pragma unroll
        for (int c = 0; c < 2; ++c)
#pragma unroll
            for (int vt = 0; vt < 4; ++vt) {
                bf16x8 vf = *(const bf16x8*)&lV[cur][vt * 16 + col][c * 32 + quad * 8];
                o[vt] = MFMA(vf, pbf[c], o[vt]);
            }
        __builtin_amdgcn_s_setprio(0);

        if (it < 15) WRITE_V(nxt)
    }

    float l = lsum;
    l += __shfl_xor(l, 16, 64);
    l += __shfl_xor(l, 32, 64);
    const float inv = 1.f / l;

    const int qrow = qt * 64 + wave * 16 + col;
    bf16* dst = attn_out + ((size_t)b * 1024 + qrow) * 768 + h * 64;
#pragma unroll
    for (int vt = 0; vt < 4; ++vt) {
        bf16x4v pk;
#pragma unroll
        for (int r = 0; r < 4; ++r) pk[r] = (bf16)(o[vt][r] * inv);
        *(bf16x4v*)(dst + vt * 16 + quad * 4) = pk;
    }
#undef STAGE_K
#undef LOAD_V
#undef WRITE_V
}

// ---------------------------------------------------------------------------
// Out projection: out[4096][768] = aout @ woutT^T + bias (fp32 out)
// 64m x 64n tiles -> 1D grid 768 (3 blocks/CU vs 1.5 at 128x64), glds
// double-buffered, XCD-aware (each XCD owns 12bx x 8by).
// ---------------------------------------------------------------------------
__launch_bounds__(256, 3)
__global__ void k_gemm_out(const bf16* __restrict__ aout, const bf16* __restrict__ woutT,
                           const float* __restrict__ bias, float* __restrict__ out) {
    __shared__ bf16 lA[2][64][32];
    __shared__ bf16 lB[2][64][32];

    const int tid  = threadIdx.x;
    const int lane = tid & 63, wave = tid >> 6;
    const int quad = lane >> 4, col = lane & 15;
    const int sw2  = (col >> 1) & 3;
    const int wm = (wave >> 1) * 32, wn = (wave & 1) * 32;

    const int fid = blockIdx.x;
    const int xcd = fid & 7, s = fid >> 3;     // s in [0,96)
    const int bx = s % 12;                     // [0,12)
    const int by = xcd * 8 + s / 12;           // [0,64)

    const int mBase = by * 64, nBase = bx * 64;

    const bf16* Ap = aout  + (size_t)mBase * 768;
    const bf16* Bp = woutT + (size_t)nBase * 768;

#define STAGE_O(buf, k0)                                                        \
    {                                                                           \
        int idx = wave * 64 + lane;                                             \
        int row = idx >> 2, c = (idx & 3) ^ ((row >> 1) & 3);                   \
        __builtin_amdgcn_global_load_lds(                                       \
            (const glob_u32*)(Ap + (size_t)row * 768 + (k0) + c * 8),           \
            (lds_u32*)((char*)&lA[buf][0][0] + wave * 1024), 16, 0, 0);         \
        __builtin_amdgcn_global_load_lds(                                       \
            (const glob_u32*)(Bp + (size_t)row * 768 + (k0) + c * 8),           \
            (lds_u32*)((char*)&lB[buf][0][0] + wave * 1024), 16, 0, 0);         \
    }

    f32x4 acc[2][2];
#pragma unroll
    for (int mi = 0; mi < 2; ++mi)
#pragma unroll
        for (int ni = 0; ni < 2; ++ni) acc[mi][ni] = f32x4{0.f, 0.f, 0.f, 0.f};

    STAGE_O(0, 0)
    for (int it = 0; it < 24; ++it) {
        const int cur = it & 1, nxt = cur ^ 1;
        __syncthreads();
        if (it < 23) STAGE_O(nxt, (it + 1) * 32)

        bf16x8 af[2], bfg[2];
#pragma unroll
        for (int mi = 0; mi < 2; ++mi)
            af[mi]  = *(const bf16x8*)&lA[cur][wm + mi * 16 + col][(quad ^ sw2) * 8];
#pragma unroll
        for (int ni = 0; ni < 2; ++ni)
            bfg[ni] = *(const bf16x8*)&lB[cur][wn + ni * 16 + col][(quad ^ sw2) * 8];
#pragma unroll
        for (int mi = 0; mi < 2; ++mi)
#pragma unroll
            for (int ni = 0; ni < 2; ++ni)
                acc[mi][ni] = MFMA(af[mi], bfg[ni], acc[mi][ni]);
    }
#undef STAGE_O

#pragma unroll
    for (int mi = 0; mi < 2; ++mi)
#pragma unroll
        for (int ni = 0; ni < 2; ++ni)
#pragma unroll
            for (int r = 0; r < 4; ++r) {
                int m = mBase + wm + mi * 16 + quad * 4 + r;
                int n = nBase + wn + ni * 16 + col;
                out[(size_t)m * 768 + n] = acc[mi][ni][r] + bias[n];
            }
}

// ---------------------------------------------------------------------------
// Workspace layout (bytes): total 57409536 B
// ---------------------------------------------------------------------------
extern "C" void kernel_launch(void* const* d_in, const int* in_sizes, int n_in,
                              void* d_out, int out_size, void* d_ws, size_t ws_size,
                              hipStream_t stream) {
    const float* x        = (const float*)d_in[0];
    const float* pos      = (const float*)d_in[1];
    const float* w_qkv    = (const float*)d_in[2];
    const float* w_qk_pos = (const float*)d_in[3];
    const float* w_out    = (const float*)d_in[4];
    const float* b_out    = (const float*)d_in[5];
    float* out = (float*)d_out;

    char* ws = (char*)d_ws;
    bf16* xb      = (bf16*)(ws);
    bf16* posb    = (bf16*)(ws + 6291456);
    bf16* wqkvT   = (bf16*)(ws + 12582912);
    bf16* wqkposT = (bf16*)(ws + 16121856);
    bf16* woutT   = (bf16*)(ws + 18481152);
    bf16* qcat    = (bf16*)(ws + 19660800);
    bf16* kcat    = (bf16*)(ws + 32243712);
    bf16* vT      = (bf16*)(ws + 44826624);
    bf16* aout    = (bf16*)(ws + 51118080);

    k_prep<<<9600, 256, 0, stream>>>(x, pos, w_qkv, w_qk_pos, w_out,
                                     xb, posb, wqkvT, wqkposT, woutT);
    k_gemm12<<<960, 256, 0, stream>>>(xb, posb, wqkvT, wqkposT, qcat, kcat, vT);
    k_attn<<<768, 256, 0, stream>>>(qcat, kcat, vT, aout);
    k_gemm_out<<<768, 256, 0, stream>>>(aout, woutT, b_out, out);
}

// Round 12
// 173.213 us; speedup vs baseline: 1.3687x; 1.0158x over previous
//
#include <hip/hip_runtime.h>
#include <cstdint>
#include <cstddef>

typedef __bf16 bf16;
typedef __bf16 bf16x8 __attribute__((ext_vector_type(8)));
typedef __bf16 bf16x4v __attribute__((ext_vector_type(4)));
typedef float  f32x4  __attribute__((ext_vector_type(4)));

#define MFMA(a, b, c) __builtin_amdgcn_mfma_f32_16x16x32_bf16((a), (b), (c), 0, 0, 0)

typedef __attribute__((address_space(3))) unsigned int  lds_u32;
typedef __attribute__((address_space(1))) unsigned int glob_u32;

// B=4, N=1024, DIM=768, HEADS=12, DIM_HEAD=64, INNER=768
// c2 = 0.5/sqrt(768)*log2(e) is folded into qcat by k_gemm12's epilogue.

// ---------------------------------------------------------------------------
// Merged prep: blocks [0,6144) = fp32->bf16 convert of x|pos;
// blocks [6144,9600) = transposing convert of the 3 weights.
// ---------------------------------------------------------------------------
__global__ void k_prep(const float* __restrict__ x, const float* __restrict__ pos,
                       const float* __restrict__ w_qkv, const float* __restrict__ w_qk_pos,
                       const float* __restrict__ w_out,
                       bf16* __restrict__ xb, bf16* __restrict__ posb,
                       bf16* __restrict__ wqkvT, bf16* __restrict__ wqkposT,
                       bf16* __restrict__ woutT) {
    __shared__ float t[32][33];
    const int blk = blockIdx.x;
    if (blk < 6144) {
        int i = blk * 256 + threadIdx.x;
        const float* in = x; bf16* out = xb;
        if (i >= 786432) { i -= 786432; in = pos; out = posb; }
        float4 v = reinterpret_cast<const float4*>(in)[i];
        bf16x4v o; o[0] = (bf16)v.x; o[1] = (bf16)v.y; o[2] = (bf16)v.z; o[3] = (bf16)v.w;
        reinterpret_cast<bf16x4v*>(out)[i] = o;
        return;
    }
    int bx = (blk - 6144) % 144, ky = (blk - 6144) / 144;
    const float* in; bf16* out; int N;
    if (bx < 72)       { in = w_qkv;    out = wqkvT;   N = 2304; }
    else if (bx < 120) { in = w_qk_pos; out = wqkposT; N = 1536; bx -= 72; }
    else               { in = w_out;    out = woutT;   N = 768;  bx -= 120; }
    const int n0 = bx * 32, k0 = ky * 32;
    const int tx = threadIdx.x & 31, ty = threadIdx.x >> 5;
#pragma unroll
    for (int r = 0; r < 32; r += 8)
        t[ty + r][tx] = in[(size_t)(k0 + ty + r) * N + n0 + tx];
    __syncthreads();
#pragma unroll
    for (int r = 0; r < 32; r += 8)
        out[(size_t)(n0 + ty + r) * 768 + k0 + tx] = (bf16)t[tx][ty + r];
}

// ---------------------------------------------------------------------------
// Merged GEMM for qkv (mode 0) and qk_pos (mode 1).
// R12: 8-phase 256x256/BK=64 (m201/T3+T4+T5 port), RACE-FIXED staging.
// Panel-safety rule: a stage may target panel P only after P's last reader
// phase has passed its end-barrier (slot0: A last read P2, B last read P3;
// slot1: A last read P6, B last read P7). Stages: P0/P1: O.Bn0/Bn1 -> s1;
// P4: E2.Am0+Am1 -> s0; P5: E2.Bn1; P6: E2.Bn0; P7: O2.Am0+Am1 -> s1.
// Waits: vmcnt(0) @P3 end (newest needed staged 2 phases ago);
// vmcnt(4) @P7 end (retires P4-P6 = E2, keeps P7's O2.Am in flight).
// Prologue: T0 all + T1.Am (12 instrs), vmcnt(4) retires exactly T0.
// All fragment mappings / chunk-XOR <-> (quad^sw2)*8 pairing byte-identical
// to the R6-verified 256^2 kernel. Grid 240, 1 block/CU, LDS 128 KiB.
// ---------------------------------------------------------------------------
__launch_bounds__(512, 2)
__global__ void k_gemm12(const bf16* __restrict__ xb, const bf16* __restrict__ posb,
                         const bf16* __restrict__ wqkvT, const bf16* __restrict__ wqkposT,
                         bf16* __restrict__ qcat, bf16* __restrict__ kcat,
                         bf16* __restrict__ vT) {
    __shared__ bf16 lA[2][2][2][128][32];   // [slot][mhalf][khalf][row][col] 64 KB
    __shared__ bf16 lB[2][2][2][128][32];   // [slot][nhalf][khalf][row][col] 64 KB

    const int tid  = threadIdx.x;
    const int lane = tid & 63, wave = tid >> 6;          // wave 0..7
    const int quad = lane >> 4, col = lane & 15;
    const int sw2  = (col >> 1) & 3;
    const int rg8  = (quad ^ sw2) * 8;
    const int mh   = wave >> 2;                           // wave's M-half
    const int nh   = (wave >> 1) & 1;                     // wave's N-half (panel)
    const int nb64 = (wave & 1) * 64;                     // offset within N-panel
    const int wm   = mh * 128, wn = (wave & 3) * 64;

    const int fid = blockIdx.x;                           // grid 240
    const int xcd = fid & 7, s = fid >> 3;                // s in [0,30)
    const int bx = s % 15;                                // 9 qkv + 6 pos tiles
    const int by = xcd * 2 + s / 15;                      // [0,16)

    int mode, nBase;
    const bf16 *A, *BT;
    if (bx < 9) { mode = 0; A = xb;   BT = wqkvT;   nBase = bx * 256; }
    else        { mode = 1; A = posb; BT = wqkposT; nBase = (bx - 9) * 256; }
    const int mBase = by * 256;

    const bf16* Ap = A  + (size_t)mBase * 768;
    const bf16* Bp = BT + (size_t)nBase * 768;

    // Stage one half-tile (128 rows x 64 K) = wave w owns 16-row chunk; 2 glds
    // of 16B per thread (j = khalf). Chunk-XOR source swizzle
    // c = (lane&3)^((lane>>3)&3) pairs with the rg8 read (proven in R0/R6).
#define STAGE_A8(ss, h, t)                                                     \
    _Pragma("unroll")                                                          \
    for (int j = 0; j < 2; ++j) {                                              \
        int c = (lane & 3) ^ ((lane >> 3) & 3);                                \
        __builtin_amdgcn_global_load_lds(                                      \
            (const glob_u32*)(Ap + (size_t)((h) * 128 + wave * 16 + (lane >> 2)) * 768 \
                              + (t) * 64 + j * 32 + c * 8),                    \
            (lds_u32*)(&lA[ss][h][j][wave * 16][0]), 16, 0, 0);                \
    }
#define STAGE_B8(ss, h, t)                                                     \
    _Pragma("unroll")                                                          \
    for (int j = 0; j < 2; ++j) {                                              \
        int c = (lane & 3) ^ ((lane >> 3) & 3);                                \
        __builtin_amdgcn_global_load_lds(                                      \
            (const glob_u32*)(Bp + (size_t)((h) * 128 + wave * 16 + (lane >> 2)) * 768 \
                              + (t) * 64 + j * 32 + c * 8),                    \
            (lds_u32*)(&lB[ss][h][j][wave * 16][0]), 16, 0, 0);                \
    }

#define READ_A8(ss, mq)                                                        \
    _Pragma("unroll")                                                          \
    for (int f = 0; f < 4; ++f)                                                \
    _Pragma("unroll")                                                          \
    for (int ks = 0; ks < 2; ++ks)                                             \
        afr[f][ks] = *(const bf16x8*)&lA[ss][mh][ks][(mq) * 64 + f * 16 + col][rg8];
#define READ_B8(ss, nq)                                                        \
    _Pragma("unroll")                                                          \
    for (int n = 0; n < 2; ++n)                                                \
    _Pragma("unroll")                                                          \
    for (int ks = 0; ks < 2; ++ks)                                             \
        bfr[n][ks] = *(const bf16x8*)&lB[ss][nh][ks][nb64 + (nq) * 32 + n * 16 + col][rg8];

#define MM16(mq, nq)                                                           \
    __builtin_amdgcn_s_setprio(1);                                             \
    _Pragma("unroll")                                                          \
    for (int ks = 0; ks < 2; ++ks)                                             \
    _Pragma("unroll")                                                          \
    for (int f = 0; f < 4; ++f)                                                \
    _Pragma("unroll")                                                          \
    for (int n = 0; n < 2; ++n)                                                \
        acc[(mq) * 4 + f][(nq) * 2 + n] =                                      \
            MFMA(afr[f][ks], bfr[n][ks], acc[(mq) * 4 + f][(nq) * 2 + n]);     \
    __builtin_amdgcn_s_setprio(0);

#define BAR()   __builtin_amdgcn_s_barrier()
#define LGKM0() do { asm volatile("s_waitcnt lgkmcnt(0)" ::: "memory");        \
                     __builtin_amdgcn_sched_barrier(0); } while (0)

    f32x4 acc[8][4];
#pragma unroll
    for (int mi = 0; mi < 8; ++mi)
#pragma unroll
        for (int ni = 0; ni < 4; ++ni) acc[mi][ni] = f32x4{0.f, 0.f, 0.f, 0.f};

    bf16x8 afr[4][2], bfr[2][2];

    // Prologue: T0 complete -> slot0, T1.Am0/Am1 -> slot1 (12 instrs).
    // vmcnt(4) retires the oldest 8 = exactly T0; BAR publishes LDS.
    STAGE_A8(0, 0, 0) STAGE_A8(0, 1, 0)
    STAGE_B8(0, 0, 0)
    STAGE_B8(0, 1, 0)
    STAGE_A8(1, 0, 1) STAGE_A8(1, 1, 1)
    asm volatile("s_waitcnt vmcnt(4)" ::: "memory");
    BAR();

    for (int i = 0; i < 6; ++i) {
        const int tO = 2 * i + 1, tE2 = 2 * i + 2, tO2 = 2 * i + 3;
        // ---- P0: s0 q(0,0); stage O.Bn0 -> s1 (s1 B free since prev P7) ----
        READ_A8(0, 0) READ_B8(0, 0)
        STAGE_B8(1, 0, tO)
        BAR(); LGKM0();
        MM16(0, 0)
        BAR();
        // ---- P1: s0 q(0,1), A reuse; stage O.Bn1 -> s1 ----
        READ_B8(0, 1)
        STAGE_B8(1, 1, tO)
        BAR(); LGKM0();
        MM16(0, 1)
        BAR();
        // ---- P2: s0 q(1,1), B reuse; NO stage (s0 still being read) ----
        READ_A8(0, 1)
        BAR(); LGKM0();
        MM16(1, 1)
        BAR();
        // ---- P3: s0 q(1,0); vmcnt(0): O fully landed (newest = P1, 2ph) ----
        READ_B8(0, 0)
        BAR(); LGKM0();
        MM16(1, 0)
        asm volatile("s_waitcnt vmcnt(0)" ::: "memory");
        BAR();
        // ---- P4: s1 q(0,0); stage E2.Am0+Am1 -> s0 (s0 free after P3) ----
        READ_A8(1, 0) READ_B8(1, 0)
        if (i < 5) { STAGE_A8(0, 0, tE2) STAGE_A8(0, 1, tE2) }
        BAR(); LGKM0();
        MM16(0, 0)
        BAR();
        // ---- P5: s1 q(0,1), A reuse; stage E2.Bn1 -> s0 ----
        READ_B8(1, 1)
        if (i < 5) STAGE_B8(0, 1, tE2)
        BAR(); LGKM0();
        MM16(0, 1)
        BAR();
        // ---- P6: s1 q(1,1), B reuse; stage E2.Bn0 -> s0 ----
        READ_A8(1, 1)
        if (i < 5) STAGE_B8(0, 0, tE2)
        BAR(); LGKM0();
        MM16(1, 1)
        BAR();
        // ---- P7: s1 q(1,0); stage O2.Am0+Am1 -> s1 (s1 A free after P6);
        //      vmcnt(4): retires P4-P6 (= E2 complete), keeps O2.Am in flight.
        READ_B8(1, 0)
        if (i < 5) { STAGE_A8(1, 0, tO2) STAGE_A8(1, 1, tO2) }
        BAR(); LGKM0();
        MM16(1, 0)
        if (i < 5) { asm volatile("s_waitcnt vmcnt(4)" ::: "memory"); }
        BAR();
    }
#undef STAGE_A8
#undef STAGE_B8
#undef READ_A8
#undef READ_B8
#undef MM16
#undef BAR
#undef LGKM0

    // Epilogue (verbatim R5/R6, harness-verified): 256-tile never straddles
    // the q/k/v boundaries (768 = 3*256) -> `which` block-uniform.
    const float c2s = 0.018042195912f * 1.44269504089f;
    const int bb = mBase >> 10;
    const int sr0 = (mBase & 1023) + wm + quad * 4;
    const int which = (mode == 0) ? (nBase >= 1536 ? 2 : (nBase >= 768 ? 1 : 0))
                                  : (nBase >= 768 ? 1 : 0);
#pragma unroll
    for (int ni = 0; ni < 4; ++ni) {
        const int nb = nBase + wn + ni * 16;
        const int rem = nb - which * 768;
        const int hh = rem >> 6, dd0 = rem & 63;
        const size_t hb = (size_t)(bb * 12 + hh);
        if (mode == 0 && which == 2) {
            bf16* dstv = vT + (hb * 64 + dd0 + col) * 1024 + sr0;
#pragma unroll
            for (int mi = 0; mi < 8; ++mi) {
                bf16x4v pk;
#pragma unroll
                for (int r = 0; r < 4; ++r) pk[r] = (bf16)acc[mi][ni][r];
                *(bf16x4v*)(dstv + mi * 16) = pk;
            }
        } else {
            const float scl = (which == 0) ? c2s : 1.0f;
            bf16* dstq = (which == 0 ? qcat : kcat)
                       + (hb * 1024 + sr0) * 128 + (mode == 1 ? 64 : 0) + dd0 + col;
#pragma unroll
            for (int mi = 0; mi < 8; ++mi)
#pragma unroll
                for (int r = 0; r < 4; ++r)
                    dstq[(size_t)(mi * 16 + r) * 128] = (bf16)(acc[mi][ni][r] * scl);
        }
    }
}

// ---------------------------------------------------------------------------
// Flash attention v5 + T5 setprio (R10: within noise, kept per m191).
// Register-resident P + conflict-free V via PADDED [64][72] sigma-permuted
// LDS tile. v6 lesson (R9): direct-from-global V is address-divergent (lane
// stride 2KB -> 64 cache lines per instruction) -> 36 -> 99 us. LDS sigma-
// permutation exists precisely to keep staging loads coalesced.
// K staging via glds. LDS 50.6 KB -> 3 blocks/CU. Grid 768 XCD-pinned.
// ---------------------------------------------------------------------------
__launch_bounds__(256, 3)
__global__ void k_attn(const bf16* __restrict__ qcat, const bf16* __restrict__ kcat,
                       const bf16* __restrict__ vT, bf16* __restrict__ attn_out) {
    __shared__ bf16 lK[2][64][128];   // 32 KB, XOR-swizzled chunks (glds)
    __shared__ bf16 lV[2][64][72];    // 18.4 KB, padded + sigma-permuted

    const int tid  = threadIdx.x;
    const int lane = tid & 63, wave = tid >> 6;
    const int quad = lane >> 4, col = lane & 15;
    const int sw   = col & 7;

    const int fid = blockIdx.x;
    const int xcd = fid & 7, s = fid >> 3;
    const int qt = s & 15;
    const int unit = (s >> 4) * 8 + xcd;
    const int b = unit / 12, h = unit % 12;

    const bf16* Qb = qcat + (size_t)unit * 1024 * 128;
    const bf16* Kb = kcat + (size_t)unit * 1024 * 128;
    const bf16* Vb = vT   + (size_t)unit * 64 * 1024;

    const int kidx = wave * 256 + lane;

#define STAGE_K(buf, kv0)                                                      \
    _Pragma("unroll")                                                          \
    for (int j = 0; j < 4; ++j) {                                              \
        int idx = kidx + j * 64;                                               \
        int row = idx >> 4, c = idx & 15, csrc = c ^ (row & 7);                \
        __builtin_amdgcn_global_load_lds(                                      \
            (const glob_u32*)(Kb + (size_t)((kv0) + row) * 128 + csrc * 8),    \
            (lds_u32*)(&lK[buf][0][0] + (wave * 4 + j) * 512), 16, 0, 0);      \
    }

    int vdj[2], vsk[2], vka[2];
#pragma unroll
    for (int j = 0; j < 2; ++j) {
        int cid = wave * 128 + j * 64 + lane;
        vdj[j] = cid >> 3;
        int sck = cid & 7;
        vsk[j] = sck * 8;
        vka[j] = (sck >> 2) * 32 + (sck & 1) * 16 + ((sck >> 1) & 1) * 4;
    }

#define LOAD_V(kv0)                                                            \
    _Pragma("unroll")                                                          \
    for (int j = 0; j < 2; ++j)                                                \
        vreg[j] = *(const uint4*)(Vb + (size_t)vdj[j] * 1024 + (kv0) + vsk[j]);
#define WRITE_V(buf)                                                           \
    _Pragma("unroll")                                                          \
    for (int j = 0; j < 2; ++j) {                                               \
        *(uint2*)&lV[buf][vdj[j]][vka[j]]     = make_uint2(vreg[j].x, vreg[j].y);\
        *(uint2*)&lV[buf][vdj[j]][vka[j] + 8] = make_uint2(vreg[j].z, vreg[j].w);\
    }

    bf16x8 qb[4];
    {
        const bf16* qrow = Qb + (size_t)(qt * 64 + wave * 16 + col) * 128;
#pragma unroll
        for (int f = 0; f < 4; ++f) qb[f] = *(const bf16x8*)(qrow + f * 32 + quad * 8);
    }

    f32x4 o[4];
#pragma unroll
    for (int vt = 0; vt < 4; ++vt) o[vt] = f32x4{0.f, 0.f, 0.f, 0.f};
    float lsum = 0.f;

    uint4 vreg[2];
    STAGE_K(0, 0)
    LOAD_V(0)
    WRITE_V(0)

    for (int it = 0; it < 16; ++it) {
        const int cur = it & 1, nxt = cur ^ 1;
        __syncthreads();
        if (it < 15) {
            const int kv1 = (it + 1) * 64;
            STAGE_K(nxt, kv1)
            LOAD_V(kv1)
        }

        // S^T = K * Q^T : A-frag = K rows (m = kv_local = t*16+col)
        f32x4 st[4];
#pragma unroll
        for (int t = 0; t < 4; ++t) st[t] = f32x4{0.f, 0.f, 0.f, 0.f};
        __builtin_amdgcn_s_setprio(1);
#pragma unroll
        for (int t = 0; t < 4; ++t)
#pragma unroll
            for (int f = 0; f < 4; ++f) {
                bf16x8 kf = *(const bf16x8*)&lK[cur][t * 16 + col][((f * 4 + quad) ^ sw) * 8];
                st[t] = MFMA(kf, qb[f], st[t]);
            }
        __builtin_amdgcn_s_setprio(0);

        // p = exp2(s); pack into PV B-fragments
        bf16x8 pbf[2];
#pragma unroll
        for (int c = 0; c < 2; ++c) {
#pragma unroll
            for (int r = 0; r < 4; ++r) {
                float p0 = exp2f(st[2 * c][r]);
                float p1 = exp2f(st[2 * c + 1][r]);
                lsum += p0 + p1;
                pbf[c][r]     = (bf16)p0;
                pbf[c][4 + r] = (bf16)p1;
            }
        }

        // O^T += V^T * P^T ; V fragment = ONE b128 from sigma-permuted tile
        __builtin_amdgcn_s_setprio(1);
#pragma unroll
        for (int c = 0; c < 2; ++c)
#pragma unroll
            for (int vt = 0; vt < 4; ++vt) {
                bf16x8 vf = *(const bf16x8*)&lV[cur][vt * 16 + col][c * 32 + quad * 8];
                o[vt] = MFMA(vf, pbf[c], o[vt]);
            }
        __builtin_amdgcn_s_setprio(0);

        if (it < 15) WRITE_V(nxt)
    }

    float l = lsum;
    l += __shfl_xor(l, 16, 64);
    l += __shfl_xor(l, 32, 64);
    const float inv = 1.f / l;

    const int qrow = qt * 64 + wave * 16 + col;
    bf16* dst = attn_out + ((size_t)b * 1024 + qrow) * 768 + h * 64;
#pragma unroll
    for (int vt = 0; vt < 4; ++vt) {
        bf16x4v pk;
#pragma unroll
        for (int r = 0; r < 4; ++r) pk[r] = (bf16)(o[vt][r] * inv);
        *(bf16x4v*)(dst + vt * 16 + quad * 4) = pk;
    }
#undef STAGE_K
#undef LOAD_V
#undef WRITE_V
}

// ---------------------------------------------------------------------------
// Out projection: out[4096][768] = aout @ woutT^T + bias (fp32 out)
// 64m x 64n tiles -> 1D grid 768 (3 blocks/CU), glds double-buffered,
// XCD-aware (each XCD owns 12bx x 8by).
// ---------------------------------------------------------------------------
__launch_bounds__(256, 3)
__global__ void k_gemm_out(const bf16* __restrict__ aout, const bf16* __restrict__ woutT,
                           const float* __restrict__ bias, float* __restrict__ out) {
    __shared__ bf16 lA[2][64][32];
    __shared__ bf16 lB[2][64][32];

    const int tid  = threadIdx.x;
    const int lane = tid & 63, wave = tid >> 6;
    const int quad = lane >> 4, col = lane & 15;
    const int sw2  = (col >> 1) & 3;
    const int wm = (wave >> 1) * 32, wn = (wave & 1) * 32;

    const int fid = blockIdx.x;
    const int xcd = fid & 7, s = fid >> 3;     // s in [0,96)
    const int bx = s % 12;                     // [0,12)
    const int by = xcd * 8 + s / 12;           // [0,64)

    const int mBase = by * 64, nBase = bx * 64;

    const bf16* Ap = aout  + (size_t)mBase * 768;
    const bf16* Bp = woutT + (size_t)nBase * 768;

#define STAGE_O(buf, k0)                                                        \
    {                                                                           \
        int idx = wave * 64 + lane;                                             \
        int row = idx >> 2, c = (idx & 3) ^ ((row >> 1) & 3);                   \
        __builtin_amdgcn_global_load_lds(                                       \
            (const glob_u32*)(Ap + (size_t)row * 768 + (k0) + c * 8),           \
            (lds_u32*)((char*)&lA[buf][0][0] + wave * 1024), 16, 0, 0);         \
        __builtin_amdgcn_global_load_lds(                                       \
            (const glob_u32*)(Bp + (size_t)row * 768 + (k0) + c * 8),           \
            (lds_u32*)((char*)&lB[buf][0][0] + wave * 1024), 16, 0, 0);         \
    }

    f32x4 acc[2][2];
#pragma unroll
    for (int mi = 0; mi < 2; ++mi)
#pragma unroll
        for (int ni = 0; ni < 2; ++ni) acc[mi][ni] = f32x4{0.f, 0.f, 0.f, 0.f};

    STAGE_O(0, 0)
    for (int it = 0; it < 24; ++it) {
        const int cur = it & 1, nxt = cur ^ 1;
        __syncthreads();
        if (it < 23) STAGE_O(nxt, (it + 1) * 32)

        bf16x8 af[2], bfg[2];
#pragma unroll
        for (int mi = 0; mi < 2; ++mi)
            af[mi]  = *(const bf16x8*)&lA[cur][wm + mi * 16 + col][(quad ^ sw2) * 8];
#pragma unroll
        for (int ni = 0; ni < 2; ++ni)
            bfg[ni] = *(const bf16x8*)&lB[cur][wn + ni * 16 + col][(quad ^ sw2) * 8];
#pragma unroll
        for (int mi = 0; mi < 2; ++mi)
#pragma unroll
            for (int ni = 0; ni < 2; ++ni)
                acc[mi][ni] = MFMA(af[mi], bfg[ni], acc[mi][ni]);
    }
#undef STAGE_O

#pragma unroll
    for (int mi = 0; mi < 2; ++mi)
#pragma unroll
        for (int ni = 0; ni < 2; ++ni)
#pragma unroll
            for (int r = 0; r < 4; ++r) {
                int m = mBase + wm + mi * 16 + quad * 4 + r;
                int n = nBase + wn + ni * 16 + col;
                out[(size_t)m * 768 + n] = acc[mi][ni][r] + bias[n];
            }
}

// ---------------------------------------------------------------------------
// Workspace layout (bytes): total 57409536 B
// ---------------------------------------------------------------------------
extern "C" void kernel_launch(void* const* d_in, const int* in_sizes, int n_in,
                              void* d_out, int out_size, void* d_ws, size_t ws_size,
                              hipStream_t stream) {
    const float* x        = (const float*)d_in[0];
    const float* pos      = (const float*)d_in[1];
    const float* w_qkv    = (const float*)d_in[2];
    const float* w_qk_pos = (const float*)d_in[3];
    const float* w_out    = (const float*)d_in[4];
    const float* b_out    = (const float*)d_in[5];
    float* out = (float*)d_out;

    char* ws = (char*)d_ws;
    bf16* xb      = (bf16*)(ws);
    bf16* posb    = (bf16*)(ws + 6291456);
    bf16* wqkvT   = (bf16*)(ws + 12582912);
    bf16* wqkposT = (bf16*)(ws + 16121856);
    bf16* woutT   = (bf16*)(ws + 18481152);
    bf16* qcat    = (bf16*)(ws + 19660800);
    bf16* kcat    = (bf16*)(ws + 32243712);
    bf16* vT      = (bf16*)(ws + 44826624);
    bf16* aout    = (bf16*)(ws + 51118080);

    k_prep<<<9600, 256, 0, stream>>>(x, pos, w_qkv, w_qk_pos, w_out,
                                     xb, posb, wqkvT, wqkposT, woutT);
    k_gemm12<<<240, 512, 0, stream>>>(xb, posb, wqkvT, wqkposT, qcat, kcat, vT);
    k_attn<<<768, 256, 0, stream>>>(qcat, kcat, vT, aout);
    k_gemm_out<<<768, 256, 0, stream>>>(aout, woutT, b_out, out);
}